// Round 3
// baseline (1238.065 us; speedup 1.0000x reference)
//
#include <hip/hip_runtime.h>
#include <hip/hip_bf16.h>
#include <cstddef>

constexpr int kB = 512;   // batch
constexpr int kN = 256;   // sequence
constexpr int kH = 512;   // hidden
constexpr int kBN = kB * kN;

typedef __attribute__((ext_vector_type(8))) short short8v;
typedef __attribute__((ext_vector_type(4))) short short4v;
typedef __attribute__((ext_vector_type(4))) float f32x4;

__device__ __forceinline__ float fast_tanh(float x) {
  x = fminf(fmaxf(x, -15.f), 15.f);
  float e = __expf(2.f * x);
  return (e - 1.f) / (e + 1.f);
}

__device__ __forceinline__ short bf_hi_bits(float x) {
  __hip_bfloat16 h = __float2bfloat16(x);
  return *reinterpret_cast<short*>(&h);
}
__device__ __forceinline__ float bf_to_f(short s) {
  __hip_bfloat16 h = *reinterpret_cast<__hip_bfloat16*>(&s);
  return __bfloat162float(h);
}

// K0: split Ws[k][c] fp32 -> WsT_hi/lo[c][k] bf16 bits (transposed, k-major)
__global__ __launch_bounds__(256) void k_splitws(const float* __restrict__ Ws,
                                                 short* __restrict__ BThi,
                                                 short* __restrict__ BTlo) {
  const int c = blockIdx.x;
  for (int k = threadIdx.x; k < kH; k += 256) {
    float x = Ws[(size_t)k * kH + c];
    short hb = bf_hi_bits(x);
    short lb = bf_hi_bits(x - bf_to_f(hb));
    BThi[(size_t)c * kH + k] = hb;
    BTlo[(size_t)c * kH + k] = lb;
  }
}

// K1: wresp[b,k] = sum_h tr[b,h] * Wr[h,k]   (fp32, tiny)
__global__ __launch_bounds__(256) void k_wresp(const float* __restrict__ tr,
                                               const float* __restrict__ Wr,
                                               float* __restrict__ wresp) {
  __shared__ float trs[8][kH];
  const int t = threadIdx.x;
  const int b0 = blockIdx.x * 8;
  for (int i = t; i < 8 * kH; i += 256)
    trs[i >> 9][i & 511] = tr[(size_t)b0 * kH + i];
  __syncthreads();
  float acc0[8] = {}, acc1[8] = {};
  for (int h = 0; h < kH; ++h) {
    float w0 = Wr[(size_t)h * kH + t];
    float w1 = Wr[(size_t)h * kH + t + 256];
#pragma unroll
    for (int bb = 0; bb < 8; ++bb) {
      float x = trs[bb][h];
      acc0[bb] += x * w0;
      acc1[bb] += x * w1;
    }
  }
#pragma unroll
  for (int bb = 0; bb < 8; ++bb) {
    wresp[(size_t)(b0 + bb) * kH + t] = acc0[bb];
    wresp[(size_t)(b0 + bb) * kH + t + 256] = acc1[bb];
  }
}

// K2: MFMA bf16x3-split fused score GEMM.
// scores[r] = mask[r] * sum_c tanh( (A[r,:] @ Ws)[c] + wresp[b,c] ) * w[c]
// Block: 64 rows, 256 threads = 4 waves = (2 row-blocks of 32) x (2 col-halves of 256).
// Wave tile: 32 rows x 256 cols = 2x16 fragments (16x16x32 MFMA).
// K in 8 chunks of 64. A staged fp32->bf16(hi/lo) per chunk; Ws^T staged per
// (chunk, 128-col step). LDS XOR-swizzle (row&7)<<4 on write+read.
__global__ __launch_bounds__(256, 2) void k_scores_mfma(
    const float* __restrict__ A, const short* __restrict__ BThi,
    const short* __restrict__ BTlo, const float* __restrict__ wresp,
    const float* __restrict__ wvec, const float* __restrict__ mask,
    float* __restrict__ scores) {
  __shared__ short Ahi[64 * 64], Alo[64 * 64];    // [row][k] swizzled, 8 KB ea
  __shared__ short Bhi[128 * 64], Blo[128 * 64];  // [colidx][k] swizzled, 16 KB ea
  __shared__ float scr[2][64];

  const int t = threadIdx.x;
  const int r0 = blockIdx.x * 64;
  const int b = r0 >> 8;
  const int w = t >> 6, l = t & 63;
  const int r2 = w & 1, c2 = w >> 1;   // row-block, col-half
  const int l15 = l & 15, l4 = l >> 4;

  f32x4 acc[2][16];
#pragma unroll
  for (int rf = 0; rf < 2; ++rf)
#pragma unroll
    for (int ci = 0; ci < 16; ++ci) acc[rf][ci] = (f32x4){0.f, 0.f, 0.f, 0.f};

  for (int kt = 0; kt < 8; ++kt) {
    __syncthreads();  // previous iter's compute done before overwriting A/B
    // ---- stage A chunk [64 rows][64 k], fp32 -> hi/lo bf16, swizzled ----
#pragma unroll
    for (int q = 0; q < 4; ++q) {
      const int fi = t + q * 256;          // 1024 float4 total
      const int row = fi >> 4, kq = fi & 15;
      const float4 v = *reinterpret_cast<const float4*>(
          A + (size_t)(r0 + row) * kH + kt * 64 + kq * 4);
      const float vv[4] = {v.x, v.y, v.z, v.w};
      short4v hv, lv;
#pragma unroll
      for (int j = 0; j < 4; ++j) {
        short hb = bf_hi_bits(vv[j]);
        hv[j] = hb;
        lv[j] = bf_hi_bits(vv[j] - bf_to_f(hb));
      }
      const int byte = (row * 128 + kq * 8) ^ ((row & 7) << 4);
      *reinterpret_cast<short4v*>(reinterpret_cast<char*>(Ahi) + byte) = hv;
      *reinterpret_cast<short4v*>(reinterpret_cast<char*>(Alo) + byte) = lv;
    }
    __syncthreads();  // A visible

    // ---- load A fragments for this chunk (hoisted across js) ----
    short8v afh[2][2], afl[2][2];  // [rf][ks]
#pragma unroll
    for (int rf = 0; rf < 2; ++rf)
#pragma unroll
      for (int ks = 0; ks < 2; ++ks) {
        const int row = r2 * 32 + rf * 16 + l15;
        const int kb = (ks * 32 + l4 * 8) * 2;
        const int byte = (row * 128 + kb) ^ ((row & 7) << 4);
        afh[rf][ks] = *reinterpret_cast<const short8v*>(
            reinterpret_cast<const char*>(Ahi) + byte);
        afl[rf][ks] = *reinterpret_cast<const short8v*>(
            reinterpret_cast<const char*>(Alo) + byte);
      }

    for (int js = 0; js < 4; ++js) {
      if (js > 0) __syncthreads();  // prior js compute done before B overwrite
      // ---- stage B: cols {js*64..+63} of half0 and half1, [128][64] ----
#pragma unroll
      for (int q = 0; q < 4; ++q) {
        const int si = t + q * 256;  // 1024 short8 per dtype
        const int col = si >> 3, kq = si & 7;
        const int colg = (col < 64) ? (js * 64 + col) : (256 + js * 64 + col - 64);
        const size_t goff = (size_t)colg * kH + kt * 64 + kq * 8;
        const int byte = (col * 128 + kq * 16) ^ ((col & 7) << 4);
        *reinterpret_cast<short8v*>(reinterpret_cast<char*>(Bhi) + byte) =
            *reinterpret_cast<const short8v*>(BThi + goff);
        *reinterpret_cast<short8v*>(reinterpret_cast<char*>(Blo) + byte) =
            *reinterpret_cast<const short8v*>(BTlo + goff);
      }
      __syncthreads();  // B visible

      // ---- MFMA: 4 col-frags x 2 ksteps x (2 reads + 6 MFMAs) ----
#pragma unroll
      for (int cf = 0; cf < 4; ++cf) {
        const int colidx = c2 * 64 + cf * 16 + l15;
        const int ci = js * 4 + cf;
#pragma unroll
        for (int ks = 0; ks < 2; ++ks) {
          const int kb = (ks * 32 + l4 * 8) * 2;
          const int byte = (colidx * 128 + kb) ^ ((colidx & 7) << 4);
          const short8v bh = *reinterpret_cast<const short8v*>(
              reinterpret_cast<const char*>(Bhi) + byte);
          const short8v bl = *reinterpret_cast<const short8v*>(
              reinterpret_cast<const char*>(Blo) + byte);
#pragma unroll
          for (int rf = 0; rf < 2; ++rf) {
            acc[rf][ci] = __builtin_amdgcn_mfma_f32_16x16x32_bf16(
                afh[rf][ks], bh, acc[rf][ci], 0, 0, 0);
            acc[rf][ci] = __builtin_amdgcn_mfma_f32_16x16x32_bf16(
                afh[rf][ks], bl, acc[rf][ci], 0, 0, 0);
            acc[rf][ci] = __builtin_amdgcn_mfma_f32_16x16x32_bf16(
                afl[rf][ks], bh, acc[rf][ci], 0, 0, 0);
          }
        }
      }
    }
  }

  // ---- epilogue: tanh + dot(w), reduce across 16 lanes, combine halves ----
  float wr[16], wv[16];
#pragma unroll
  for (int ci = 0; ci < 16; ++ci) {
    const int colg = c2 * 256 + ci * 16 + l15;
    wr[ci] = wresp[(size_t)b * kH + colg];
    wv[ci] = wvec[colg];
  }
#pragma unroll
  for (int rf = 0; rf < 2; ++rf)
#pragma unroll
    for (int j = 0; j < 4; ++j) {
      float s = 0.f;
#pragma unroll
      for (int ci = 0; ci < 16; ++ci)
        s += fast_tanh(acc[rf][ci][j] + wr[ci]) * wv[ci];
      s += __shfl_xor(s, 1, 64);
      s += __shfl_xor(s, 2, 64);
      s += __shfl_xor(s, 4, 64);
      s += __shfl_xor(s, 8, 64);
      if (l15 == 0) scr[c2][r2 * 32 + rf * 16 + l4 * 4 + j] = s;
    }
  __syncthreads();
  if (t < 64) scores[r0 + t] = (scr[0][t] + scr[1][t]) * mask[r0 + t];
}

// K3: per-b softmax over N -> alpha; resp_raw[b,:] = sum_n alpha*A[b,n,:]
__global__ __launch_bounds__(256) void k_softmax_wsum(
    const float* __restrict__ scores, const float* __restrict__ A,
    float* __restrict__ alpha, float* __restrict__ resp_raw) {
  __shared__ float al[kN];
  __shared__ float redm[4], reds[4];
  const int b = blockIdx.x, t = threadIdx.x;
  const int wid = t >> 6, lane = t & 63;
  float s = scores[(size_t)b * kN + t];
  float m = s;
#pragma unroll
  for (int off = 1; off < 64; off <<= 1) m = fmaxf(m, __shfl_xor(m, off, 64));
  if (lane == 0) redm[wid] = m;
  __syncthreads();
  m = fmaxf(fmaxf(redm[0], redm[1]), fmaxf(redm[2], redm[3]));
  float p = __expf(s - m);
  float sum = p;
#pragma unroll
  for (int off = 1; off < 64; off <<= 1) sum += __shfl_xor(sum, off, 64);
  if (lane == 0) reds[wid] = sum;
  __syncthreads();
  sum = reds[0] + reds[1] + reds[2] + reds[3];
  const float a = p / sum;
  al[t] = a;
  alpha[(size_t)b * kN + t] = a;
  __syncthreads();
  const float2* Arow = reinterpret_cast<const float2*>(A + (size_t)b * kN * kH);
  float2 acc = {0.f, 0.f};
#pragma unroll 8
  for (int n = 0; n < kN; ++n) {
    const float an = al[n];
    const float2 v = Arow[(size_t)n * 256 + t];
    acc.x += an * v.x;
    acc.y += an * v.y;
  }
  *reinterpret_cast<float2*>(resp_raw + (size_t)b * kH + 2 * t) = acc;
}

// K4: out[b,o] = tanh( rr[b,:]·Wp[o,:] + tr[b,:]·Wx[o,:] )
__global__ __launch_bounds__(256) void k_final(const float* __restrict__ rr,
                                               const float* __restrict__ tr,
                                               const float* __restrict__ Wp,
                                               const float* __restrict__ Wx,
                                               float* __restrict__ out) {
  __shared__ float rrs[8][kH];
  __shared__ float trs[8][kH];
  const int t = threadIdx.x;
  const int b0 = blockIdx.x * 8;
  for (int i = t; i < 8 * kH; i += 256) {
    rrs[i >> 9][i & 511] = rr[(size_t)b0 * kH + i];
    trs[i >> 9][i & 511] = tr[(size_t)b0 * kH + i];
  }
  __syncthreads();
  const int w = t >> 6, lane = t & 63;
  for (int o = w; o < kH; o += 4) {
    const float* wp = Wp + (size_t)o * kH;
    const float* wx = Wx + (size_t)o * kH;
    float acc[8] = {};
    for (int hb = 0; hb < kH; hb += 64) {
      const float p = wp[hb + lane];
      const float x = wx[hb + lane];
#pragma unroll
      for (int bb = 0; bb < 8; ++bb)
        acc[bb] += p * rrs[bb][hb + lane] + x * trs[bb][hb + lane];
    }
#pragma unroll
    for (int bb = 0; bb < 8; ++bb) {
      float v = acc[bb];
#pragma unroll
      for (int off = 1; off < 64; off <<= 1) v += __shfl_xor(v, off, 64);
      if (lane == bb) out[(size_t)(b0 + bb) * kH + o] = fast_tanh(v);
    }
  }
}

extern "C" void kernel_launch(void* const* d_in, const int* in_sizes, int n_in,
                              void* d_out, int out_size, void* d_ws,
                              size_t ws_size, hipStream_t stream) {
  const float* spk_emb = (const float*)d_in[0];  // [B,N,H]
  const float* mask = (const float*)d_in[1];     // [B,N]
  const float* tr = (const float*)d_in[2];       // [B,H]
  const float* Ws = (const float*)d_in[3];       // [H,H]
  const float* Wr = (const float*)d_in[4];       // [H,H]
  const float* wvec = (const float*)d_in[5];     // [H]
  const float* Wp = (const float*)d_in[6];       // [H,H] (out,in)
  const float* Wx = (const float*)d_in[7];       // [H,H] (out,in)

  float* out = (float*)d_out;
  float* resp_out = out;                     // [B,H]
  float* alpha_out = out + (size_t)kB * kH;  // [B,N]

  char* ws = (char*)d_ws;
  float* wresp = (float*)ws;                                   // 1 MB
  float* scores = (float*)(ws + (1u << 20));                   // 512 KB
  float* resp_raw = (float*)(ws + (1u << 20) + (1u << 19));    // 1 MB
  short* BThi = (short*)(ws + (5u << 19));                     // 512 KB
  short* BTlo = (short*)(ws + (6u << 19));                     // 512 KB

  k_splitws<<<kH, 256, 0, stream>>>(Ws, BThi, BTlo);
  k_wresp<<<kB / 8, 256, 0, stream>>>(tr, Wr, wresp);
  k_scores_mfma<<<kBN / 64, 256, 0, stream>>>(spk_emb, BThi, BTlo, wresp, wvec,
                                              mask, scores);
  k_softmax_wsum<<<kB, 256, 0, stream>>>(scores, spk_emb, alpha_out, resp_raw);
  k_final<<<kB / 8, 256, 0, stream>>>(resp_raw, tr, Wp, Wx, resp_out);
}

// Round 4
// 734.945 us; speedup vs baseline: 1.6846x; 1.6846x over previous
//
#include <hip/hip_runtime.h>
#include <hip/hip_bf16.h>
#include <cstddef>

constexpr int kB = 512;   // batch
constexpr int kN = 256;   // sequence
constexpr int kH = 512;   // hidden
constexpr int kBN = kB * kN;

typedef __attribute__((ext_vector_type(8))) short short8v;
typedef __attribute__((ext_vector_type(4))) short short4v;
typedef __attribute__((ext_vector_type(4))) float f32x4;

__device__ __forceinline__ float fast_tanh(float x) {
  x = fminf(fmaxf(x, -15.f), 15.f);
  float e = __expf(2.f * x);
  return (e - 1.f) / (e + 1.f);
}

__device__ __forceinline__ short bf_hi_bits(float x) {
  __hip_bfloat16 h = __float2bfloat16(x);
  return *reinterpret_cast<short*>(&h);
}
__device__ __forceinline__ float bf_to_f(short s) {
  __hip_bfloat16 h = *reinterpret_cast<__hip_bfloat16*>(&s);
  return __bfloat162float(h);
}

// K0: split Ws[k][c] fp32 -> fragment-major bf16 hi/lo:
// Bf[cq][kk][lane][j] = Ws^T[cq*16 + (lane&15)][kk*32 + (lane>>4)*8 + j]
// so a wave's (cq,kk) B-fragment load is one contiguous 1KB read.
__global__ __launch_bounds__(256) void k_splitws(const float* __restrict__ Ws,
                                                 short* __restrict__ Bfh,
                                                 short* __restrict__ Bfl) {
  const int g = blockIdx.x * 256 + threadIdx.x;  // 0..32767
  const int cq = g >> 10, kk = (g >> 6) & 15, l = g & 63;
  const int c = cq * 16 + (l & 15);
  const int kbase = kk * 32 + (l >> 4) * 8;
  short8v hv, lv;
#pragma unroll
  for (int j = 0; j < 8; ++j) {
    float x = Ws[(size_t)(kbase + j) * kH + c];
    short hb = bf_hi_bits(x);
    hv[j] = hb;
    lv[j] = bf_hi_bits(x - bf_to_f(hb));
  }
  *reinterpret_cast<short8v*>(reinterpret_cast<char*>(Bfh) + (size_t)g * 16) = hv;
  *reinterpret_cast<short8v*>(reinterpret_cast<char*>(Bfl) + (size_t)g * 16) = lv;
}

// K1: wresp[b,k] = sum_h tr[b,h] * Wr[h,k]   (512 blocks, 1 batch row each)
__global__ __launch_bounds__(256) void k_wresp(const float* __restrict__ tr,
                                               const float* __restrict__ Wr,
                                               float* __restrict__ wresp) {
  __shared__ float trs[kH];
  const int b = blockIdx.x, t = threadIdx.x;
  trs[t] = tr[(size_t)b * kH + t];
  trs[t + 256] = tr[(size_t)b * kH + t + 256];
  __syncthreads();
  float a0 = 0.f, a1 = 0.f;
#pragma unroll 8
  for (int h = 0; h < kH; ++h) {
    const float x = trs[h];
    a0 += x * Wr[(size_t)h * kH + t];
    a1 += x * Wr[(size_t)h * kH + t + 256];
  }
  wresp[(size_t)b * kH + t] = a0;
  wresp[(size_t)b * kH + t + 256] = a1;
}

// K2: fused score GEMM, bf16x3 split MFMA.
// scores[r] = mask[r] * sum_c tanh( (A[r,:]@Ws)[c] + wresp[b,c] ) * w[c]
// Block: 32 rows, 4 waves; wave w owns col-quarter w (128 cols) = 2rf x 8cf
// frags of 16x16x32. K in 8 chunks of 64. A: LDS double-buffer, XOR-swizzled,
// issue-early/write-late (1 barrier per kt). B: global->reg, frag-major,
// 1-deep static software pipeline.
__global__ __launch_bounds__(256, 3) void k_scores_mfma(
    const float* __restrict__ A, const short* __restrict__ Bfh,
    const short* __restrict__ Bfl, const float* __restrict__ wresp,
    const float* __restrict__ wvec, const float* __restrict__ mask,
    float* __restrict__ scores) {
  __shared__ short Abuf[2][2][32 * 64];  // [dbuf][hi/lo], 4KB each, swizzled
  __shared__ float scr[4][32];

  const int t = threadIdx.x;
  const int r0 = blockIdx.x * 32;
  const int b = r0 >> 8;
  const int w = t >> 6, l = t & 63;  // w = col-quarter
  const int l15 = l & 15, l4 = l >> 4;

  f32x4 acc[2][8];
#pragma unroll
  for (int rf = 0; rf < 2; ++rf)
#pragma unroll
    for (int cf = 0; cf < 8; ++cf) acc[rf][cf] = (f32x4){0.f, 0.f, 0.f, 0.f};

  // ---- A staging helpers (fp32 -> hi/lo bf16, swizzled) ----
  const int srow = t >> 4;          // 0..31 (fi = t + q*256 -> row = fi>>4)
  const int skq = t & 15;           // float4 index within row
  const int sbyte0 = ((srow)*128 + skq * 8) ^ ((srow & 7) << 4);
  const int srow1 = (t + 256) >> 4, skq1 = t & 15;
  const int sbyte1 = ((srow1)*128 + skq1 * 8) ^ ((srow1 & 7) << 4);

  float4 av0, av1;
  // prologue: load + stage A chunk kt=0 into buf 0
  av0 = *reinterpret_cast<const float4*>(A + (size_t)(r0 + srow) * kH + skq * 4);
  av1 = *reinterpret_cast<const float4*>(A + (size_t)(r0 + srow1) * kH + skq1 * 4);
  {
    short4v hv, lv;
    const float v0[4] = {av0.x, av0.y, av0.z, av0.w};
#pragma unroll
    for (int j = 0; j < 4; ++j) {
      short hb = bf_hi_bits(v0[j]);
      hv[j] = hb;
      lv[j] = bf_hi_bits(v0[j] - bf_to_f(hb));
    }
    *reinterpret_cast<short4v*>(reinterpret_cast<char*>(Abuf[0][0]) + sbyte0) = hv;
    *reinterpret_cast<short4v*>(reinterpret_cast<char*>(Abuf[0][1]) + sbyte0) = lv;
    const float v1[4] = {av1.x, av1.y, av1.z, av1.w};
#pragma unroll
    for (int j = 0; j < 4; ++j) {
      short hb = bf_hi_bits(v1[j]);
      hv[j] = hb;
      lv[j] = bf_hi_bits(v1[j] - bf_to_f(hb));
    }
    *reinterpret_cast<short4v*>(reinterpret_cast<char*>(Abuf[0][0]) + sbyte1) = hv;
    *reinterpret_cast<short4v*>(reinterpret_cast<char*>(Abuf[0][1]) + sbyte1) = lv;
  }
  __syncthreads();

  const size_t lane16 = (size_t)l * 16;
  const char* BfhC = reinterpret_cast<const char*>(Bfh);
  const char* BflC = reinterpret_cast<const char*>(Bfl);

  for (int kt = 0; kt < 8; ++kt) {
    const int p = kt & 1;
    // issue next A-tile loads early (hide HBM under MFMA)
    if (kt < 7) {
      av0 = *reinterpret_cast<const float4*>(A + (size_t)(r0 + srow) * kH +
                                             (kt + 1) * 64 + skq * 4);
      av1 = *reinterpret_cast<const float4*>(A + (size_t)(r0 + srow1) * kH +
                                             (kt + 1) * 64 + skq1 * 4);
    }
    // A fragments for this chunk
    short8v afh[2][2], afl[2][2];  // [rf][ks]
#pragma unroll
    for (int rf = 0; rf < 2; ++rf)
#pragma unroll
      for (int ks = 0; ks < 2; ++ks) {
        const int row = rf * 16 + l15;
        const int byte = (row * 128 + (ks * 32 + l4 * 8) * 2) ^ ((row & 7) << 4);
        afh[rf][ks] = *reinterpret_cast<const short8v*>(
            reinterpret_cast<const char*>(Abuf[p][0]) + byte);
        afl[rf][ks] = *reinterpret_cast<const short8v*>(
            reinterpret_cast<const char*>(Abuf[p][1]) + byte);
      }

    // B: frag-major, base for (cq = w*8+cf, kk = kt*2+ks)
#define LOADB(S, CF)                                                        \
  do {                                                                      \
    const size_t base =                                                     \
        ((size_t)(((w * 8 + (CF)) * 16) + kt * 2) << 10) + lane16;          \
    S##h0 = *reinterpret_cast<const short8v*>(BfhC + base);                 \
    S##h1 = *reinterpret_cast<const short8v*>(BfhC + base + 1024);          \
    S##l0 = *reinterpret_cast<const short8v*>(BflC + base);                 \
    S##l1 = *reinterpret_cast<const short8v*>(BflC + base + 1024);          \
  } while (0)
#define MFMA3(ACC, AH, AL, BH, BL)                                      \
  ACC = __builtin_amdgcn_mfma_f32_16x16x32_bf16(AH, BH, ACC, 0, 0, 0);  \
  ACC = __builtin_amdgcn_mfma_f32_16x16x32_bf16(AH, BL, ACC, 0, 0, 0);  \
  ACC = __builtin_amdgcn_mfma_f32_16x16x32_bf16(AL, BH, ACC, 0, 0, 0);
#define DOCF(S, CF)                                              \
  MFMA3(acc[0][CF], afh[0][0], afl[0][0], S##h0, S##l0);         \
  MFMA3(acc[1][CF], afh[1][0], afl[1][0], S##h0, S##l0);         \
  MFMA3(acc[0][CF], afh[0][1], afl[0][1], S##h1, S##l1);         \
  MFMA3(acc[1][CF], afh[1][1], afl[1][1], S##h1, S##l1);

    short8v s0h0, s0h1, s0l0, s0l1, s1h0, s1h1, s1l0, s1l1;
    LOADB(s0, 0);
    LOADB(s1, 1); DOCF(s0, 0);
    LOADB(s0, 2); DOCF(s1, 1);
    LOADB(s1, 3); DOCF(s0, 2);
    LOADB(s0, 4); DOCF(s1, 3);
    LOADB(s1, 5); DOCF(s0, 4);
    LOADB(s0, 6); DOCF(s1, 5);
    LOADB(s1, 7); DOCF(s0, 6);
    DOCF(s1, 7);

    // write next A tile (loads have had the whole MFMA cluster to land)
    if (kt < 7) {
      short4v hv, lv;
      const float v0[4] = {av0.x, av0.y, av0.z, av0.w};
#pragma unroll
      for (int j = 0; j < 4; ++j) {
        short hb = bf_hi_bits(v0[j]);
        hv[j] = hb;
        lv[j] = bf_hi_bits(v0[j] - bf_to_f(hb));
      }
      *reinterpret_cast<short4v*>(reinterpret_cast<char*>(Abuf[p ^ 1][0]) + sbyte0) = hv;
      *reinterpret_cast<short4v*>(reinterpret_cast<char*>(Abuf[p ^ 1][1]) + sbyte0) = lv;
      const float v1[4] = {av1.x, av1.y, av1.z, av1.w};
#pragma unroll
      for (int j = 0; j < 4; ++j) {
        short hb = bf_hi_bits(v1[j]);
        hv[j] = hb;
        lv[j] = bf_hi_bits(v1[j] - bf_to_f(hb));
      }
      *reinterpret_cast<short4v*>(reinterpret_cast<char*>(Abuf[p ^ 1][0]) + sbyte1) = hv;
      *reinterpret_cast<short4v*>(reinterpret_cast<char*>(Abuf[p ^ 1][1]) + sbyte1) = lv;
    }
    __syncthreads();
  }

  // epilogue: tanh + dot(w), reduce across l15, combine quarters via LDS
  float wr[8], wv8[8];
#pragma unroll
  for (int cf = 0; cf < 8; ++cf) {
    const int colg = w * 128 + cf * 16 + l15;
    wr[cf] = wresp[(size_t)b * kH + colg];
    wv8[cf] = wvec[colg];
  }
#pragma unroll
  for (int rf = 0; rf < 2; ++rf)
#pragma unroll
    for (int j = 0; j < 4; ++j) {
      float s = 0.f;
#pragma unroll
      for (int cf = 0; cf < 8; ++cf)
        s += fast_tanh(acc[rf][cf][j] + wr[cf]) * wv8[cf];
      s += __shfl_xor(s, 1, 64);
      s += __shfl_xor(s, 2, 64);
      s += __shfl_xor(s, 4, 64);
      s += __shfl_xor(s, 8, 64);
      if (l15 == 0) scr[w][rf * 16 + l4 * 4 + j] = s;
    }
  __syncthreads();
  if (t < 32)
    scores[r0 + t] =
        (scr[0][t] + scr[1][t] + scr[2][t] + scr[3][t]) * mask[r0 + t];
}

// K3: per-b softmax over N -> alpha; resp_raw[b,:] = sum_n alpha*A[b,n,:]
__global__ __launch_bounds__(256) void k_softmax_wsum(
    const float* __restrict__ scores, const float* __restrict__ A,
    float* __restrict__ alpha, float* __restrict__ resp_raw) {
  __shared__ float al[kN];
  __shared__ float redm[4], reds[4];
  const int b = blockIdx.x, t = threadIdx.x;
  const int wid = t >> 6, lane = t & 63;
  float s = scores[(size_t)b * kN + t];
  float m = s;
#pragma unroll
  for (int off = 1; off < 64; off <<= 1) m = fmaxf(m, __shfl_xor(m, off, 64));
  if (lane == 0) redm[wid] = m;
  __syncthreads();
  m = fmaxf(fmaxf(redm[0], redm[1]), fmaxf(redm[2], redm[3]));
  float p = __expf(s - m);
  float sum = p;
#pragma unroll
  for (int off = 1; off < 64; off <<= 1) sum += __shfl_xor(sum, off, 64);
  if (lane == 0) reds[wid] = sum;
  __syncthreads();
  sum = reds[0] + reds[1] + reds[2] + reds[3];
  const float a = p / sum;
  al[t] = a;
  alpha[(size_t)b * kN + t] = a;
  __syncthreads();
  const float2* Arow = reinterpret_cast<const float2*>(A + (size_t)b * kN * kH);
  float2 acc = {0.f, 0.f};
#pragma unroll 8
  for (int n = 0; n < kN; ++n) {
    const float an = al[n];
    const float2 v = Arow[(size_t)n * 256 + t];
    acc.x += an * v.x;
    acc.y += an * v.y;
  }
  *reinterpret_cast<float2*>(resp_raw + (size_t)b * kH + 2 * t) = acc;
}

// K4: out[b,o] = tanh( rr[b,:]·Wp[o,:] + tr[b,:]·Wx[o,:] )  (512 blocks)
__global__ __launch_bounds__(256) void k_final(const float* __restrict__ rr,
                                               const float* __restrict__ tr,
                                               const float* __restrict__ Wp,
                                               const float* __restrict__ Wx,
                                               float* __restrict__ out) {
  __shared__ float rrs[kH];
  __shared__ float trs[kH];
  const int b = blockIdx.x, t = threadIdx.x;
  rrs[t] = rr[(size_t)b * kH + t];
  rrs[t + 256] = rr[(size_t)b * kH + t + 256];
  trs[t] = tr[(size_t)b * kH + t];
  trs[t + 256] = tr[(size_t)b * kH + t + 256];
  __syncthreads();
  const int w = t >> 6, lane = t & 63;
  for (int o = w; o < kH; o += 4) {
    const float* wp = Wp + (size_t)o * kH;
    const float* wx = Wx + (size_t)o * kH;
    float acc = 0.f;
#pragma unroll
    for (int hb = 0; hb < kH; hb += 64)
      acc += wp[hb + lane] * rrs[hb + lane] + wx[hb + lane] * trs[hb + lane];
#pragma unroll
    for (int off = 1; off < 64; off <<= 1) acc += __shfl_xor(acc, off, 64);
    if (lane == 0) out[(size_t)b * kH + o] = fast_tanh(acc);
  }
}

extern "C" void kernel_launch(void* const* d_in, const int* in_sizes, int n_in,
                              void* d_out, int out_size, void* d_ws,
                              size_t ws_size, hipStream_t stream) {
  const float* spk_emb = (const float*)d_in[0];  // [B,N,H]
  const float* mask = (const float*)d_in[1];     // [B,N]
  const float* tr = (const float*)d_in[2];       // [B,H]
  const float* Ws = (const float*)d_in[3];       // [H,H]
  const float* Wr = (const float*)d_in[4];       // [H,H]
  const float* wvec = (const float*)d_in[5];     // [H]
  const float* Wp = (const float*)d_in[6];       // [H,H] (out,in)
  const float* Wx = (const float*)d_in[7];       // [H,H] (out,in)

  float* out = (float*)d_out;
  float* resp_out = out;                     // [B,H]
  float* alpha_out = out + (size_t)kB * kH;  // [B,N]

  char* ws = (char*)d_ws;
  float* wresp = (float*)ws;                                 // 1 MB
  float* scores = (float*)(ws + (1u << 20));                 // 512 KB
  float* resp_raw = (float*)(ws + (1u << 20) + (1u << 19));  // 1 MB
  short* Bfh = (short*)(ws + (5u << 19));                    // 512 KB
  short* Bfl = (short*)(ws + (6u << 19));                    // 512 KB

  k_splitws<<<128, 256, 0, stream>>>(Ws, Bfh, Bfl);
  k_wresp<<<kB, 256, 0, stream>>>(tr, Wr, wresp);
  k_scores_mfma<<<kBN / 32, 256, 0, stream>>>(spk_emb, Bfh, Bfl, wresp, wvec,
                                              mask, scores);
  k_softmax_wsum<<<kB, 256, 0, stream>>>(scores, spk_emb, alpha_out, resp_raw);
  k_final<<<kB, 256, 0, stream>>>(resp_raw, tr, Wp, Wx, resp_out);
}